// Round 2
// baseline (3617.173 us; speedup 1.0000x reference)
//
#include <hip/hip_runtime.h>
#include <hip/hip_fp16.h>

#define T_LEN 1024
#define E_DIM 300
#define H_DIM 512
#define D_DIM 1024
#define K_TAGS 12
#define G4 2048   // 4*H

static __device__ __forceinline__ float frcp(float x){ return __builtin_amdgcn_rcpf(x); }
static __device__ __forceinline__ float sigm(float x){ return frcp(1.f + __expf(-x)); }
// overflow-safe fast tanh: tanh(x) = sign(x) * (1 - 2/(e^{2|x|}+1))
static __device__ __forceinline__ float ftanh(float x){
  const float e = __expf(2.f * fabsf(x));
  const float t = 1.f - 2.f * frcp(e + 1.f);
  return copysignf(t, x);
}

// ---------------- gather: x[t,e] = word_embeds[sentence[t], e] ----------------
__global__ void k_gather(const int* __restrict__ sent, const float* __restrict__ we,
                         float* __restrict__ x){
  int idx = blockIdx.x*256 + threadIdx.x;
  if (idx < T_LEN*E_DIM){
    int t = idx / E_DIM, e = idx - t*E_DIM;
    x[idx] = we[(size_t)sent[t]*E_DIM + e];
  }
}

// ---------------- zero the tagged h ring buffer (2 dir * 2 slot * 512 u32) ----
__global__ void k_init(unsigned* __restrict__ hbuf){
  int i = blockIdx.x*256 + threadIdx.x;
  if (i < 2048) hbuf[i] = 0u;  // tag 0, f16 value +0.0
}

// ---------------- generic fp32 GEMM: C = act( A(·rev?) * B(^T?) + bias ) ------
// A: [M,K] lda ; arev: use row (M-1-m)
// bt=1: C[m,n] = sum_k A[m,k]*B[n,k]  (B:[N,K] ldb)
// bt=0: C[m,n] = sum_k A[m,k]*B[k,n]  (B:[K,N] ldb)
__global__ __launch_bounds__(256) void k_gemm(
    const float* __restrict__ A, int lda, int arev,
    const float* __restrict__ B, int ldb, int bt,
    const float* __restrict__ bias, float* __restrict__ C, int ldc,
    int M, int N, int K, int act)
{
  __shared__ float As[16][65];
  __shared__ float Bs[16][65];
  const int tid = threadIdx.x;
  const int bm = blockIdx.y * 64, bn = blockIdx.x * 64;
  const int tx = tid & 15, ty = tid >> 4;
  float acc[4][4] = {};

  for (int k0 = 0; k0 < K; k0 += 16){
    {
      const int mm = tid >> 2, k4 = (tid & 3) * 4;
      const int m  = bm + mm;
      const long mi = arev ? (long)(M-1-m) : (long)m;
      #pragma unroll
      for (int i=0;i<4;i++){
        const int k = k0 + k4 + i;
        As[k4+i][mm] = (m < M && k < K) ? A[mi*(long)lda + k] : 0.f;
      }
      if (bt){
        const int nn = mm, n = bn + nn;
        #pragma unroll
        for (int i=0;i<4;i++){
          const int k = k0 + k4 + i;
          Bs[k4+i][nn] = (n < N && k < K) ? B[(size_t)n*ldb + k] : 0.f;
        }
      } else {
        const int nn = tid & 63, kb = (tid >> 6) * 4;
        #pragma unroll
        for (int r=0;r<4;r++){
          const int k = k0 + kb + r;
          Bs[kb+r][nn] = (k < K && (bn+nn) < N) ? B[(size_t)k*ldb + bn + nn] : 0.f;
        }
      }
    }
    __syncthreads();
    #pragma unroll
    for (int kk=0;kk<16;++kk){
      float a[4], b[4];
      #pragma unroll
      for (int i=0;i<4;i++){ a[i]=As[kk][ty*4+i]; b[i]=Bs[kk][tx*4+i]; }
      #pragma unroll
      for (int i=0;i<4;i++){
        #pragma unroll
        for (int j=0;j<4;j++) acc[i][j] += a[i]*b[j];
      }
    }
    __syncthreads();
  }
  #pragma unroll
  for (int i=0;i<4;i++){
    const int m = bm + ty*4 + i;
    if (m >= M) continue;
    #pragma unroll
    for (int j=0;j<4;j++){
      const int n = bn + tx*4 + j;
      if (n >= N) continue;
      float v = acc[i][j];
      if (bias) v += bias[n];
      if (act) v = ftanh(v);
      C[(size_t)m*ldc + n] = v;
    }
  }
}

// ---------------- persistent bidirectional LSTM recurrence --------------------
// 32 WGs x 512 threads. blocks 0..15: forward, 16..31: backward.
// WG w owns h-indices [w*32, w*32+32) across all 4 gates (128 rows of 2048).
// thread = (q,p): q=row-within-WG (128), p=K-quarter (4). Weights in VGPRs.
// h broadcast: hbuf[dir][slot][512] u32 words = (step_tag<<16)|f16(h).
// Critical-path design: xg[t] is register-pipeline prefetched one step ahead
// (issued before the poll, consumed next step) so the only global-latency
// items on the serial chain are the publish store + poll load (L3 round trip).
__global__ __launch_bounds__(512, 2) void k_lstm(
    const float* __restrict__ Whh_f, const float* __restrict__ Whh_b,
    const float* __restrict__ bih_f, const float* __restrict__ bhh_f,
    const float* __restrict__ bih_b, const float* __restrict__ bhh_b,
    const float* __restrict__ xg_f, const float* __restrict__ xg_b,
    unsigned* __restrict__ hbuf, float* __restrict__ enc)
{
  const int dir = blockIdx.x >> 4;
  const int w   = blockIdx.x & 15;
  const int tid = threadIdx.x;
  const int p = tid & 3, q = tid >> 2;   // q: 0..127
  const int g = q >> 5, l = q & 31;      // gate, local h index
  const int hj  = w*32 + l;              // h index 0..511
  const int row = g*H_DIM + hj;          // gate row 0..2047

  const float* Whh = dir ? Whh_b : Whh_f;
  const float* xg  = dir ? xg_b  : xg_f;
  const float bias = dir ? (bih_b[row] + bhh_b[row]) : (bih_f[row] + bhh_f[row]);

  // preload 128 weights as 32 float4, chunk order rotated by 2*p (bank-conflict-free h reads)
  float4 w4[32];
  {
    const float* wr = Whh + (size_t)row*H_DIM + p*128;
    #pragma unroll
    for (int k2=0;k2<32;k2++){
      const int c = (k2 + 2*p) & 31;
      w4[k2] = *reinterpret_cast<const float4*>(wr + 4*c);
    }
  }

  __shared__ float lds_h[512];
  __shared__ float gv[128];
  __shared__ float lds_c[32];
  if (tid < 32) lds_c[tid] = 0.f;

  unsigned* hb = hbuf + dir*1024;  // [2][512]

  // xg register pipeline: xg_cur holds the value for the current step
  float xg_cur = 0.f;
  if (p == 0) xg_cur = xg[row];    // step t=1 uses xg row 0

  for (int t = 1; t <= T_LEN; ++t){
    // prefetch next step's xg BEFORE the poll — a full step of latency cover
    float xg_nxt = 0.f;
    if (p == 0 && t < T_LEN) xg_nxt = xg[(size_t)t*G4 + row];

    // stage h_{t-1}: poll tagged word, decode f16 -> LDS f32
    {
      unsigned* src = hb + ((t-1)&1)*512 + tid;
      const unsigned want = (unsigned)(t-1);
      unsigned v = __hip_atomic_load(src, __ATOMIC_RELAXED, __HIP_MEMORY_SCOPE_AGENT);
      while ((v >> 16) != want)
        v = __hip_atomic_load(src, __ATOMIC_RELAXED, __HIP_MEMORY_SCOPE_AGENT);
      lds_h[tid] = __half2float(__ushort_as_half((unsigned short)(v & 0xffffu)));
    }
    __syncthreads();

    const float4* h4 = reinterpret_cast<const float4*>(lds_h) + p*32;
    float acc0=0.f, acc1=0.f;
    #pragma unroll
    for (int k2=0;k2<32;k2+=2){
      const int c0 = (k2     + 2*p) & 31;
      const int c1 = (k2 + 1 + 2*p) & 31;
      const float4 a0 = w4[k2],   b0 = h4[c0];
      const float4 a1 = w4[k2+1], b1 = h4[c1];
      acc0 += a0.x*b0.x + a0.y*b0.y + a0.z*b0.z + a0.w*b0.w;
      acc1 += a1.x*b1.x + a1.y*b1.y + a1.z*b1.z + a1.w*b1.w;
    }
    float acc = acc0 + acc1;
    acc += __shfl_xor(acc, 1);
    acc += __shfl_xor(acc, 2);
    if (p == 0) gv[q] = acc + bias + xg_cur;
    __syncthreads();

    if (tid < 32){
      const float iv = sigm(gv[tid]);
      const float fv = sigm(gv[32+tid]);
      const float gg = ftanh(gv[64+tid]);
      const float ov = sigm(gv[96+tid]);
      const float cc = fv*lds_c[tid] + iv*gg;
      lds_c[tid] = cc;
      const float hh = ov*ftanh(cc);
      const int jj = w*32 + tid;
      // publish FIRST (this is what other WGs are waiting on) ...
      const unsigned hv = ((unsigned)t << 16) |
                          (unsigned)__half_as_ushort(__float2half(hh));
      __hip_atomic_store(hb + (t&1)*512 + jj, hv, __ATOMIC_RELAXED, __HIP_MEMORY_SCOPE_AGENT);
      // ... then the off-path enc store
      const int tt = dir ? (T_LEN - t) : (t - 1);
      enc[(size_t)tt*D_DIM + dir*H_DIM + jj] = hh;
    }
    xg_cur = xg_nxt;
    __syncthreads();  // protect lds_h/gv reuse next iteration
  }
}

// ---------------- row softmax in place, rows of 1024 --------------------------
__global__ __launch_bounds__(256) void k_softmax(float* __restrict__ S){
  float* r = S + (size_t)blockIdx.x*1024;
  const int tid = threadIdx.x;
  float v[4];
  #pragma unroll
  for (int i=0;i<4;i++) v[i] = r[tid + i*256];
  float m = fmaxf(fmaxf(v[0],v[1]), fmaxf(v[2],v[3]));
  #pragma unroll
  for (int off=32; off>=1; off>>=1) m = fmaxf(m, __shfl_xor(m, off));
  __shared__ float red[4], red2[4];
  const int wid = tid >> 6, lane = tid & 63;
  if (lane == 0) red[wid] = m;
  __syncthreads();
  m = fmaxf(fmaxf(red[0],red[1]), fmaxf(red[2],red[3]));
  float s = 0.f;
  #pragma unroll
  for (int i=0;i<4;i++){ v[i] = __expf(v[i]-m); s += v[i]; }
  #pragma unroll
  for (int off=32; off>=1; off>>=1) s += __shfl_xor(s, off);
  if (lane == 0) red2[wid] = s;
  __syncthreads();
  s = red2[0]+red2[1]+red2[2]+red2[3];
  const float inv = frcp(s);
  #pragma unroll
  for (int i=0;i<4;i++) r[tid + i*256] = v[i]*inv;
}

// ---------------- copy enc into cat[:, 0:1024] --------------------------------
__global__ void k_copy_enc(const float* __restrict__ enc, float* __restrict__ cat){
  int idx = blockIdx.x*256 + threadIdx.x;
  if (idx < T_LEN*D_DIM){
    int t = idx >> 10, d = idx & 1023;
    cat[(size_t)t*2048 + d] = enc[idx];
  }
}

// ---------------- CRF forward + gold score, single wave -----------------------
__global__ void k_crf(const float* __restrict__ feats, const float* __restrict__ trans,
                      const int* __restrict__ tags, float* __restrict__ out){
  const int tid = threadIdx.x;  // 64 threads, one wave
  // gold path score
  float gold = 0.f;
  for (int i = tid; i <= T_LEN; i += 64){
    const int to = (i < T_LEN) ? tags[i]   : 11;      // STOP
    const int fr = (i == 0)    ? 10        : tags[i-1]; // START
    gold += trans[to*K_TAGS + fr];
    if (i < T_LEN) gold += feats[(size_t)i*K_TAGS + tags[i]];
  }
  #pragma unroll
  for (int off=32; off>=1; off>>=1) gold += __shfl_xor(gold, off);

  // forward algorithm: lane 'to' (<12) holds alpha[to]
  float Trow[K_TAGS];
  if (tid < K_TAGS){
    #pragma unroll
    for (int j=0;j<K_TAGS;j++) Trow[j] = trans[tid*K_TAGS + j];
  }
  float alpha = (tid == 10) ? 0.f : -10000.f;
  for (int t=0;t<T_LEN;++t){
    float av[K_TAGS];
    #pragma unroll
    for (int j=0;j<K_TAGS;j++) av[j] = __shfl(alpha, j);
    if (tid < K_TAGS){
      float vv[K_TAGS], m = -1e30f;
      #pragma unroll
      for (int j=0;j<K_TAGS;j++){ vv[j] = av[j] + Trow[j]; m = fmaxf(m, vv[j]); }
      float s = 0.f;
      #pragma unroll
      for (int j=0;j<K_TAGS;j++) s += __expf(vv[j]-m);
      alpha = m + __logf(s) + feats[(size_t)t*K_TAGS + tid];
    }
  }
  float v = (tid < K_TAGS) ? (alpha + trans[11*K_TAGS + tid]) : -1e30f;
  float m = v;
  #pragma unroll
  for (int off=32; off>=1; off>>=1) m = fmaxf(m, __shfl_xor(m, off));
  float e = (tid < K_TAGS) ? __expf(v - m) : 0.f;
  #pragma unroll
  for (int off=32; off>=1; off>>=1) e += __shfl_xor(e, off);
  if (tid == 0) out[0] = (m + __logf(e)) - gold;
}

// ------------------------------------------------------------------------------
extern "C" void kernel_launch(void* const* d_in, const int* in_sizes, int n_in,
                              void* d_out, int out_size, void* d_ws, size_t ws_size,
                              hipStream_t stream)
{
  const int*   sentence = (const int*)d_in[0];
  const int*   tags     = (const int*)d_in[1];
  const float* we       = (const float*)d_in[2];
  const float* Wih_f    = (const float*)d_in[3];
  const float* Whh_f    = (const float*)d_in[4];
  const float* bih_f    = (const float*)d_in[5];
  const float* bhh_f    = (const float*)d_in[6];
  const float* Wih_b    = (const float*)d_in[7];
  const float* Whh_b    = (const float*)d_in[8];
  const float* bih_b    = (const float*)d_in[9];
  const float* bhh_b    = (const float*)d_in[10];
  const float* attn_W   = (const float*)d_in[11];
  const float* attn_b   = (const float*)d_in[12];
  const float* h2h1_W   = (const float*)d_in[13];
  const float* h2h1_b   = (const float*)d_in[14];
  const float* tag_W    = (const float*)d_in[15];
  const float* tag_b    = (const float*)d_in[16];
  const float* trans    = (const float*)d_in[17];
  float* out = (float*)d_out;

  // workspace layout (floats), with lifetime-based aliasing (~25.3 MB total)
  float* ws     = (float*)d_ws;
  float* cat    = ws;                  // [1024,2048]   also xg_f
  float* reg2   = cat  + 2097152;      // [2M]          xg_b; later scores+h1
  float* enc    = reg2 + 2097152;      // [1024,1024]
  float* proj   = enc  + 1048576;      // [1024,1024]   also x (gather)
  float* feats  = proj + 1048576;      // [1024,12]
  unsigned* hbuf= (unsigned*)(feats + 12288);  // 2048 u32
  float* xg_f   = cat;
  float* xg_b   = reg2;
  float* scores = reg2;
  float* h1     = reg2 + 1048576;
  float* x      = proj;

  // 1. gather embeddings
  k_gather<<<dim3((T_LEN*E_DIM + 255)/256), dim3(256), 0, stream>>>(sentence, we, x);
  // 2. init h ring buffer (tag 0 / value 0)
  k_init<<<dim3(8), dim3(256), 0, stream>>>(hbuf);
  // 3. xg_f = x * Wih_f^T        [1024,2048]
  k_gemm<<<dim3(32,16), dim3(256), 0, stream>>>(x, E_DIM, 0, Wih_f, E_DIM, 1,
      nullptr, xg_f, G4, T_LEN, G4, E_DIM, 0);
  // 4. xg_b = rev(x) * Wih_b^T   [1024,2048]
  k_gemm<<<dim3(32,16), dim3(256), 0, stream>>>(x, E_DIM, 1, Wih_b, E_DIM, 1,
      nullptr, xg_b, G4, T_LEN, G4, E_DIM, 0);
  // 5. bidirectional recurrence -> enc [1024,1024]
  k_lstm<<<dim3(32), dim3(512), 0, stream>>>(Whh_f, Whh_b, bih_f, bhh_f,
      bih_b, bhh_b, xg_f, xg_b, hbuf, enc);
  // 6. proj = enc * attn_W^T + attn_b
  k_gemm<<<dim3(16,16), dim3(256), 0, stream>>>(enc, D_DIM, 0, attn_W, D_DIM, 1,
      attn_b, proj, D_DIM, T_LEN, D_DIM, D_DIM, 0);
  // 7. scores = enc * proj^T
  k_gemm<<<dim3(16,16), dim3(256), 0, stream>>>(enc, D_DIM, 0, proj, D_DIM, 1,
      nullptr, scores, T_LEN, T_LEN, T_LEN, D_DIM, 0);
  // 8. row softmax in place
  k_softmax<<<dim3(1024), dim3(256), 0, stream>>>(scores);
  // 9. cat[:, :1024] = enc
  k_copy_enc<<<dim3(4096), dim3(256), 0, stream>>>(enc, cat);
  // 10. cat[:, 1024:] = w * enc   (AB mode)
  k_gemm<<<dim3(16,16), dim3(256), 0, stream>>>(scores, T_LEN, 0, enc, D_DIM, 0,
      nullptr, cat + 1024, 2048, T_LEN, D_DIM, T_LEN, 0);
  // 11. h1 = tanh(cat * h2h1_W^T + h2h1_b)
  k_gemm<<<dim3(16,16), dim3(256), 0, stream>>>(cat, 2048, 0, h2h1_W, 2048, 1,
      h2h1_b, h1, D_DIM, T_LEN, D_DIM, 2048, 1);
  // 12. feats = h1 * tag_W^T + tag_b   [1024,12]
  k_gemm<<<dim3(1,16), dim3(256), 0, stream>>>(h1, D_DIM, 0, tag_W, D_DIM, 1,
      tag_b, feats, K_TAGS, T_LEN, K_TAGS, D_DIM, 0);
  // 13. CRF NLL
  k_crf<<<dim3(1), dim3(64), 0, stream>>>(feats, trans, tags, out);
}

// Round 4
// 2753.796 us; speedup vs baseline: 1.3135x; 1.3135x over previous
//
#include <hip/hip_runtime.h>
#include <hip/hip_fp16.h>

#define T_LEN 1024
#define E_DIM 300
#define H_DIM 512
#define D_DIM 1024
#define K_TAGS 12
#define G4 2048   // 4*H

typedef __attribute__((ext_vector_type(8))) short short8x;  // 8 bf16
typedef __attribute__((ext_vector_type(4))) float f32x4;

static __device__ __forceinline__ float frcp(float x){ return __builtin_amdgcn_rcpf(x); }
static __device__ __forceinline__ float sigm(float x){ return frcp(1.f + __expf(-x)); }
// overflow-safe fast tanh
static __device__ __forceinline__ float ftanh(float x){
  const float e = __expf(2.f * fabsf(x));
  const float t = 1.f - 2.f * frcp(e + 1.f);
  return copysignf(t, x);
}
// f32 -> bf16 round-to-nearest-even
static __device__ __forceinline__ unsigned short f2b(float f){
  unsigned u = __float_as_uint(f);
  return (unsigned short)((u + 0x7fffu + ((u >> 16) & 1u)) >> 16);
}
static __device__ __forceinline__ uint4 pack8(const float* s){
  uint4 o;
  o.x = (unsigned)f2b(s[0]) | ((unsigned)f2b(s[1]) << 16);
  o.y = (unsigned)f2b(s[2]) | ((unsigned)f2b(s[3]) << 16);
  o.z = (unsigned)f2b(s[4]) | ((unsigned)f2b(s[5]) << 16);
  o.w = (unsigned)f2b(s[6]) | ((unsigned)f2b(s[7]) << 16);
  return o;
}

// ---------------- gather: x[t,e] = word_embeds[sentence[t], e] ----------------
__global__ void k_gather(const int* __restrict__ sent, const float* __restrict__ we,
                         float* __restrict__ x){
  int idx = blockIdx.x*256 + threadIdx.x;
  if (idx < T_LEN*E_DIM){
    int t = idx / E_DIM, e = idx - t*E_DIM;
    x[idx] = we[(size_t)sent[t]*E_DIM + e];
  }
}

// ---------------- zero the tagged h ring buffer (2 dir * 2 slot * 512 u32) ----
__global__ void k_init(unsigned* __restrict__ hbuf){
  int i = blockIdx.x*256 + threadIdx.x;
  if (i < 2048) hbuf[i] = 0u;  // tag 0, f16 value +0.0
}

// ---------------- MFMA bf16 GEMM: C = act( A(·rev?) * B^T + bias ) ------------
// A: f32 [M][lda] (cast to bf16 in staging); arev: row M-1-m.
// B: row-major [N][ldb]; either f32 (Bf, staged-cast) or precast bf16 (Bh).
// M,N multiples of 64; K arbitrary (ragged tail zero-padded).
// Tile 64x64, BK=32, 256 thr = 4 waves in 2x2, each wave 2x2 of 16x16x32 MFMA.
// LDS row stride 40 ushorts (80B): frag reads are 2-way-bank-conflict only (free).
__global__ __launch_bounds__(256) void k_gemm_mfma(
    const float* __restrict__ Af, int lda, int arev,
    const float* __restrict__ Bf, const unsigned short* __restrict__ Bh, int ldb,
    const float* __restrict__ bias, int act,
    float* __restrict__ C, int ldc, int M, int N, int K)
{
  __shared__ __align__(16) unsigned short As[64*40];
  __shared__ __align__(16) unsigned short Bs[64*40];
  const int tid = threadIdx.x;
  const int bm = blockIdx.y*64, bn = blockIdx.x*64;
  const int r  = tid >> 2, c8 = (tid & 3) * 8;
  const int wave = tid >> 6, lane = tid & 63;
  const int wm = (wave >> 1) * 32, wn = (wave & 1) * 32;
  const int col = lane & 15, quad = lane >> 4;

  const int am = arev ? (M-1-(bm+r)) : (bm+r);
  const float* arow = Af + (size_t)am*lda;
  const float* brow = Bf ? (Bf + (size_t)(bn+r)*ldb) : (const float*)0;
  const unsigned short* brh = Bh ? (Bh + (size_t)(bn+r)*ldb) : (const unsigned short*)0;

  uint4* aw = (uint4*)(As + r*40 + c8);
  uint4* bw = (uint4*)(Bs + r*40 + c8);

  f32x4 acc[2][2];
  #pragma unroll
  for (int i=0;i<2;i++)
    #pragma unroll
    for (int j=0;j<2;j++) acc[i][j] = (f32x4){0.f,0.f,0.f,0.f};

  for (int k0 = 0; k0 < K; k0 += 32){
    uint4 avv, bvv;
    if (k0 + 32 <= K){
      avv = pack8(arow + k0 + c8);
      bvv = Bh ? *(const uint4*)(brh + k0 + c8) : pack8(brow + k0 + c8);
    } else {
      float ta[8], tb[8];
      #pragma unroll
      for (int i=0;i<8;i++){
        const int kk = k0 + c8 + i;
        ta[i] = (kk < K) ? arow[kk] : 0.f;
        tb[i] = (kk < K && Bf) ? brow[kk] : 0.f;
      }
      avv = pack8(ta); bvv = pack8(tb);
    }
    if (k0) __syncthreads();      // all waves done reading previous tile
    *aw = avv; *bw = bvv;
    __syncthreads();
    const short8x a0 = *(const short8x*)(As + (wm+col)*40    + quad*8);
    const short8x a1 = *(const short8x*)(As + (wm+16+col)*40 + quad*8);
    const short8x b0 = *(const short8x*)(Bs + (wn+col)*40    + quad*8);
    const short8x b1 = *(const short8x*)(Bs + (wn+16+col)*40 + quad*8);
    acc[0][0] = __builtin_amdgcn_mfma_f32_16x16x32_bf16(a0, b0, acc[0][0], 0, 0, 0);
    acc[0][1] = __builtin_amdgcn_mfma_f32_16x16x32_bf16(a0, b1, acc[0][1], 0, 0, 0);
    acc[1][0] = __builtin_amdgcn_mfma_f32_16x16x32_bf16(a1, b0, acc[1][0], 0, 0, 0);
    acc[1][1] = __builtin_amdgcn_mfma_f32_16x16x32_bf16(a1, b1, acc[1][1], 0, 0, 0);
  }

  // C/D layout (m89-verified): col = lane&15, row = quad*4 + reg
  #pragma unroll
  for (int mt=0;mt<2;mt++){
    #pragma unroll
    for (int nt=0;nt<2;nt++){
      const int cc = bn + wn + 16*nt + col;
      const float bs = bias ? bias[cc] : 0.f;
      #pragma unroll
      for (int i=0;i<4;i++){
        const int rr = bm + wm + 16*mt + quad*4 + i;
        float v = acc[mt][nt][i] + bs;
        if (act) v = ftanh(v);
        C[(size_t)rr*ldc + cc] = v;
      }
    }
  }
}

// ---------------- generic fp32 GEMM (kept for tiny-N feats) -------------------
__global__ __launch_bounds__(256) void k_gemm(
    const float* __restrict__ A, int lda, int arev,
    const float* __restrict__ B, int ldb, int bt,
    const float* __restrict__ bias, float* __restrict__ C, int ldc,
    int M, int N, int K, int act)
{
  __shared__ float As[16][65];
  __shared__ float Bs[16][65];
  const int tid = threadIdx.x;
  const int bm = blockIdx.y * 64, bn = blockIdx.x * 64;
  const int tx = tid & 15, ty = tid >> 4;
  float acc[4][4] = {};

  for (int k0 = 0; k0 < K; k0 += 16){
    {
      const int mm = tid >> 2, k4 = (tid & 3) * 4;
      const int m  = bm + mm;
      const long mi = arev ? (long)(M-1-m) : (long)m;
      #pragma unroll
      for (int i=0;i<4;i++){
        const int k = k0 + k4 + i;
        As[k4+i][mm] = (m < M && k < K) ? A[mi*(long)lda + k] : 0.f;
      }
      if (bt){
        const int nn = mm, n = bn + nn;
        #pragma unroll
        for (int i=0;i<4;i++){
          const int k = k0 + k4 + i;
          Bs[k4+i][nn] = (n < N && k < K) ? B[(size_t)n*ldb + k] : 0.f;
        }
      } else {
        const int nn = tid & 63, kb = (tid >> 6) * 4;
        #pragma unroll
        for (int r=0;r<4;r++){
          const int k = k0 + kb + r;
          Bs[kb+r][nn] = (k < K && (bn+nn) < N) ? B[(size_t)k*ldb + bn + nn] : 0.f;
        }
      }
    }
    __syncthreads();
    #pragma unroll
    for (int kk=0;kk<16;++kk){
      float a[4], b[4];
      #pragma unroll
      for (int i=0;i<4;i++){ a[i]=As[kk][ty*4+i]; b[i]=Bs[kk][tx*4+i]; }
      #pragma unroll
      for (int i=0;i<4;i++){
        #pragma unroll
        for (int j=0;j<4;j++) acc[i][j] += a[i]*b[j];
      }
    }
    __syncthreads();
  }
  #pragma unroll
  for (int i=0;i<4;i++){
    const int m = bm + ty*4 + i;
    if (m >= M) continue;
    #pragma unroll
    for (int j=0;j<4;j++){
      const int n = bn + tx*4 + j;
      if (n >= N) continue;
      float v = acc[i][j];
      if (bias) v += bias[n];
      if (act) v = ftanh(v);
      C[(size_t)m*ldc + n] = v;
    }
  }
}

// ---------------- persistent bidirectional LSTM recurrence (Round-0 form) -----
// 32 WGs x 512 threads. blocks 0..15: forward, 16..31: backward.
// h broadcast: hbuf[dir][slot][512] u32 = (step_tag<<16)|f16(h), AGENT scope.
__global__ __launch_bounds__(512, 2) void k_lstm(
    const float* __restrict__ Whh_f, const float* __restrict__ Whh_b,
    const float* __restrict__ bih_f, const float* __restrict__ bhh_f,
    const float* __restrict__ bih_b, const float* __restrict__ bhh_b,
    const float* __restrict__ xg_f, const float* __restrict__ xg_b,
    unsigned* __restrict__ hbuf, float* __restrict__ enc)
{
  const int dir = blockIdx.x >> 4;
  const int w   = blockIdx.x & 15;
  const int tid = threadIdx.x;
  const int p = tid & 3, q = tid >> 2;   // q: 0..127
  const int g = q >> 5, l = q & 31;      // gate, local h index
  const int hj  = w*32 + l;              // h index 0..511
  const int row = g*H_DIM + hj;          // gate row 0..2047

  const float* Whh = dir ? Whh_b : Whh_f;
  const float* xg  = dir ? xg_b  : xg_f;
  const float bias = dir ? (bih_b[row] + bhh_b[row]) : (bih_f[row] + bhh_f[row]);

  // preload 128 weights as 32 float4, chunk order rotated by 2*p
  float4 w4[32];
  {
    const float* wr = Whh + (size_t)row*H_DIM + p*128;
    #pragma unroll
    for (int k2=0;k2<32;k2++){
      const int c = (k2 + 2*p) & 31;
      w4[k2] = *reinterpret_cast<const float4*>(wr + 4*c);
    }
  }

  __shared__ float lds_h[512];
  __shared__ float gv[128];
  __shared__ float lds_c[32];
  if (tid < 32) lds_c[tid] = 0.f;

  unsigned* hb = hbuf + dir*1024;  // [2][512]

  for (int t = 1; t <= T_LEN; ++t){
    // stage h_{t-1}: poll tagged word, decode f16 -> LDS f32
    {
      unsigned* src = hb + ((t-1)&1)*512 + tid;
      const unsigned want = (unsigned)(t-1);
      unsigned v = __hip_atomic_load(src, __ATOMIC_RELAXED, __HIP_MEMORY_SCOPE_AGENT);
      while ((v >> 16) != want)
        v = __hip_atomic_load(src, __ATOMIC_RELAXED, __HIP_MEMORY_SCOPE_AGENT);
      lds_h[tid] = __half2float(__ushort_as_half((unsigned short)(v & 0xffffu)));
    }
    __syncthreads();

    float xgv = 0.f;
    if (p == 0) xgv = xg[(size_t)(t-1)*G4 + row];

    const float4* h4 = reinterpret_cast<const float4*>(lds_h) + p*32;
    float acc0=0.f, acc1=0.f;
    #pragma unroll
    for (int k2=0;k2<32;k2+=2){
      const int c0 = (k2     + 2*p) & 31;
      const int c1 = (k2 + 1 + 2*p) & 31;
      const float4 a0 = w4[k2],   b0 = h4[c0];
      const float4 a1 = w4[k2+1], b1 = h4[c1];
      acc0 += a0.x*b0.x + a0.y*b0.y + a0.z*b0.z + a0.w*b0.w;
      acc1 += a1.x*b1.x + a1.y*b1.y + a1.z*b1.z + a1.w*b1.w;
    }
    float acc = acc0 + acc1;
    acc += __shfl_xor(acc, 1);
    acc += __shfl_xor(acc, 2);
    if (p == 0) gv[q] = acc + bias + xgv;
    __syncthreads();

    if (tid < 32){
      const float iv = sigm(gv[tid]);
      const float fv = sigm(gv[32+tid]);
      const float gg = ftanh(gv[64+tid]);
      const float ov = sigm(gv[96+tid]);
      const float cc = fv*lds_c[tid] + iv*gg;
      lds_c[tid] = cc;
      const float hh = ov*ftanh(cc);
      const int jj = w*32 + tid;
      const int tt = dir ? (T_LEN - t) : (t - 1);
      enc[(size_t)tt*D_DIM + dir*H_DIM + jj] = hh;
      const unsigned hv = ((unsigned)t << 16) |
                          (unsigned)__half_as_ushort(__float2half(hh));
      __hip_atomic_store(hb + (t&1)*512 + jj, hv, __ATOMIC_RELAXED, __HIP_MEMORY_SCOPE_AGENT);
    }
    __syncthreads();  // protect lds_h/gv reuse next iteration
  }
}

// ---------------- row softmax in place, rows of 1024 --------------------------
__global__ __launch_bounds__(256) void k_softmax(float* __restrict__ S){
  float* r = S + (size_t)blockIdx.x*1024;
  const int tid = threadIdx.x;
  float v[4];
  #pragma unroll
  for (int i=0;i<4;i++) v[i] = r[tid + i*256];
  float m = fmaxf(fmaxf(v[0],v[1]), fmaxf(v[2],v[3]));
  #pragma unroll
  for (int off=32; off>=1; off>>=1) m = fmaxf(m, __shfl_xor(m, off));
  __shared__ float red[4], red2[4];
  const int wid = tid >> 6, lane = tid & 63;
  if (lane == 0) red[wid] = m;
  __syncthreads();
  m = fmaxf(fmaxf(red[0],red[1]), fmaxf(red[2],red[3]));
  float s = 0.f;
  #pragma unroll
  for (int i=0;i<4;i++){ v[i] = __expf(v[i]-m); s += v[i]; }
  #pragma unroll
  for (int off=32; off>=1; off>>=1) s += __shfl_xor(s, off);
  if (lane == 0) red2[wid] = s;
  __syncthreads();
  s = red2[0]+red2[1]+red2[2]+red2[3];
  const float inv = frcp(s);
  #pragma unroll
  for (int i=0;i<4;i++) r[tid + i*256] = v[i]*inv;
}

// ---------------- copy enc into cat[:, 0:1024] (f32) --------------------------
__global__ void k_copy_enc(const float* __restrict__ enc, float* __restrict__ cat){
  int idx = blockIdx.x*256 + threadIdx.x;
  if (idx < T_LEN*D_DIM){
    int t = idx >> 10, d = idx & 1023;
    cat[(size_t)t*2048 + d] = enc[idx];
  }
}

// ---------------- transpose-cast: encT_bf16[d][t] = bf16(enc[t][d]) -----------
__global__ __launch_bounds__(256) void k_castT(const float* __restrict__ src,
                                               unsigned short* __restrict__ dst){
  __shared__ float tile[32][33];
  const int bx = blockIdx.x*32, by = blockIdx.y*32;
  const int tx = threadIdx.x & 31, ty8 = threadIdx.x >> 5;  // ty8: 0..7
  #pragma unroll
  for (int i=ty8;i<32;i+=8) tile[i][tx] = src[(size_t)(by+i)*1024 + bx+tx];
  __syncthreads();
  #pragma unroll
  for (int i=ty8;i<32;i+=8) dst[(size_t)(bx+i)*1024 + by+tx] = f2b(tile[tx][i]);
}

// ---------------- CRF forward + gold score, single wave -----------------------
__global__ void k_crf(const float* __restrict__ feats, const float* __restrict__ trans,
                      const int* __restrict__ tags, float* __restrict__ out){
  const int tid = threadIdx.x;  // 64 threads, one wave
  float gold = 0.f;
  for (int i = tid; i <= T_LEN; i += 64){
    const int to = (i < T_LEN) ? tags[i]   : 11;        // STOP
    const int fr = (i == 0)    ? 10        : tags[i-1]; // START
    gold += trans[to*K_TAGS + fr];
    if (i < T_LEN) gold += feats[(size_t)i*K_TAGS + tags[i]];
  }
  #pragma unroll
  for (int off=32; off>=1; off>>=1) gold += __shfl_xor(gold, off);

  float Trow[K_TAGS];
  if (tid < K_TAGS){
    #pragma unroll
    for (int j=0;j<K_TAGS;j++) Trow[j] = trans[tid*K_TAGS + j];
  }
  float alpha = (tid == 10) ? 0.f : -10000.f;
  for (int t=0;t<T_LEN;++t){
    float av[K_TAGS];
    #pragma unroll
    for (int j=0;j<K_TAGS;j++) av[j] = __shfl(alpha, j);
    if (tid < K_TAGS){
      float vv[K_TAGS], m = -1e30f;
      #pragma unroll
      for (int j=0;j<K_TAGS;j++){ vv[j] = av[j] + Trow[j]; m = fmaxf(m, vv[j]); }
      float s = 0.f;
      #pragma unroll
      for (int j=0;j<K_TAGS;j++) s += __expf(vv[j]-m);
      alpha = m + __logf(s) + feats[(size_t)t*K_TAGS + tid];
    }
  }
  float v = (tid < K_TAGS) ? (alpha + trans[11*K_TAGS + tid]) : -1e30f;
  float m = v;
  #pragma unroll
  for (int off=32; off>=1; off>>=1) m = fmaxf(m, __shfl_xor(m, off));
  float e = (tid < K_TAGS) ? __expf(v - m) : 0.f;
  #pragma unroll
  for (int off=32; off>=1; off>>=1) e += __shfl_xor(e, off);
  if (tid == 0) out[0] = (m + __logf(e)) - gold;
}

// ------------------------------------------------------------------------------
extern "C" void kernel_launch(void* const* d_in, const int* in_sizes, int n_in,
                              void* d_out, int out_size, void* d_ws, size_t ws_size,
                              hipStream_t stream)
{
  const int*   sentence = (const int*)d_in[0];
  const int*   tags     = (const int*)d_in[1];
  const float* we       = (const float*)d_in[2];
  const float* Wih_f    = (const float*)d_in[3];
  const float* Whh_f    = (const float*)d_in[4];
  const float* bih_f    = (const float*)d_in[5];
  const float* bhh_f    = (const float*)d_in[6];
  const float* Wih_b    = (const float*)d_in[7];
  const float* Whh_b    = (const float*)d_in[8];
  const float* bih_b    = (const float*)d_in[9];
  const float* bhh_b    = (const float*)d_in[10];
  const float* attn_W   = (const float*)d_in[11];
  const float* attn_b   = (const float*)d_in[12];
  const float* h2h1_W   = (const float*)d_in[13];
  const float* h2h1_b   = (const float*)d_in[14];
  const float* tag_W    = (const float*)d_in[15];
  const float* tag_b    = (const float*)d_in[16];
  const float* trans    = (const float*)d_in[17];
  float* out = (float*)d_out;

  // workspace layout (floats) — identical footprint to the proven Round-0 pool
  float* ws     = (float*)d_ws;
  float* cat    = ws;                  // [1024,2048]   also xg_f
  float* reg2   = cat  + 2097152;      // [2M]          xg_b; later scores+h1
  float* enc    = reg2 + 2097152;      // [1024,1024]
  float* proj   = enc  + 1048576;      // [1024,1024]   also x; later encT_bf16
  float* feats  = proj + 1048576;      // [1024,12]
  unsigned* hbuf= (unsigned*)(feats + 12288);  // 2048 u32
  float* xg_f   = cat;
  float* xg_b   = reg2;
  float* scores = reg2;
  float* h1     = reg2 + 1048576;
  float* x      = proj;
  unsigned short* encT = (unsigned short*)proj;  // 2 MiB, used after proj dead

  // 1. gather embeddings
  k_gather<<<dim3((T_LEN*E_DIM + 255)/256), dim3(256), 0, stream>>>(sentence, we, x);
  // 2. init h ring buffer
  k_init<<<dim3(8), dim3(256), 0, stream>>>(hbuf);
  // 3. xg_f = x * Wih_f^T        [1024,2048], K=300 ragged
  k_gemm_mfma<<<dim3(32,16), dim3(256), 0, stream>>>(x, E_DIM, 0,
      Wih_f, nullptr, E_DIM, nullptr, 0, xg_f, G4, T_LEN, G4, E_DIM);
  // 4. xg_b = rev(x) * Wih_b^T   [1024,2048]
  k_gemm_mfma<<<dim3(32,16), dim3(256), 0, stream>>>(x, E_DIM, 1,
      Wih_b, nullptr, E_DIM, nullptr, 0, xg_b, G4, T_LEN, G4, E_DIM);
  // 5. bidirectional recurrence -> enc [1024,1024]
  k_lstm<<<dim3(32), dim3(512), 0, stream>>>(Whh_f, Whh_b, bih_f, bhh_f,
      bih_b, bhh_b, xg_f, xg_b, hbuf, enc);
  // 6. proj = enc * attn_W^T + attn_b
  k_gemm_mfma<<<dim3(16,16), dim3(256), 0, stream>>>(enc, D_DIM, 0,
      attn_W, nullptr, D_DIM, attn_b, 0, proj, D_DIM, T_LEN, D_DIM, D_DIM);
  // 7. scores = enc * proj^T
  k_gemm_mfma<<<dim3(16,16), dim3(256), 0, stream>>>(enc, D_DIM, 0,
      proj, nullptr, D_DIM, nullptr, 0, scores, T_LEN, T_LEN, T_LEN, D_DIM);
  // 8. row softmax in place
  k_softmax<<<dim3(1024), dim3(256), 0, stream>>>(scores);
  // 9. cat[:, :1024] = enc   (f32)
  k_copy_enc<<<dim3(4096), dim3(256), 0, stream>>>(enc, cat);
  // 10. encT_bf16 = enc^T    (proj region is dead now)
  k_castT<<<dim3(32,32), dim3(256), 0, stream>>>(enc, encT);
  // 11. cat[:, 1024:] = w * enc  via A=w, B=encT (bf16 precast)
  k_gemm_mfma<<<dim3(16,16), dim3(256), 0, stream>>>(scores, T_LEN, 0,
      nullptr, encT, D_DIM, nullptr, 0, cat + 1024, 2048, T_LEN, D_DIM, T_LEN);
  // 12. h1 = tanh(cat * h2h1_W^T + h2h1_b), K=2048
  k_gemm_mfma<<<dim3(16,16), dim3(256), 0, stream>>>(cat, 2048, 0,
      h2h1_W, nullptr, 2048, h2h1_b, 1, h1, D_DIM, T_LEN, D_DIM, 2048);
  // 13. feats = h1 * tag_W^T + tag_b   [1024,12]  (fp32 path, tiny N)
  k_gemm<<<dim3(1,16), dim3(256), 0, stream>>>(h1, D_DIM, 0, tag_W, D_DIM, 1,
      tag_b, feats, K_TAGS, T_LEN, K_TAGS, D_DIM, 0);
  // 14. CRF NLL
  k_crf<<<dim3(1), dim3(64), 0, stream>>>(feats, trans, tags, out);
}

// Round 5
// 2107.207 us; speedup vs baseline: 1.7166x; 1.3068x over previous
//
#include <hip/hip_runtime.h>
#include <hip/hip_fp16.h>

#define T_LEN 1024
#define E_DIM 300
#define H_DIM 512
#define D_DIM 1024
#define K_TAGS 12
#define G4 2048   // 4*H

typedef __attribute__((ext_vector_type(8))) short short8x;  // 8 bf16
typedef __attribute__((ext_vector_type(4))) float f32x4;

static __device__ __forceinline__ float frcp(float x){ return __builtin_amdgcn_rcpf(x); }
static __device__ __forceinline__ float sigm(float x){ return frcp(1.f + __expf(-x)); }
// overflow-safe fast tanh
static __device__ __forceinline__ float ftanh(float x){
  const float e = __expf(2.f * fabsf(x));
  const float t = 1.f - 2.f * frcp(e + 1.f);
  return copysignf(t, x);
}
// f32 -> bf16 round-to-nearest-even
static __device__ __forceinline__ unsigned short f2b(float f){
  unsigned u = __float_as_uint(f);
  return (unsigned short)((u + 0x7fffu + ((u >> 16) & 1u)) >> 16);
}
static __device__ __forceinline__ uint4 pack8(const float* s){
  uint4 o;
  o.x = (unsigned)f2b(s[0]) | ((unsigned)f2b(s[1]) << 16);
  o.y = (unsigned)f2b(s[2]) | ((unsigned)f2b(s[3]) << 16);
  o.z = (unsigned)f2b(s[4]) | ((unsigned)f2b(s[5]) << 16);
  o.w = (unsigned)f2b(s[6]) | ((unsigned)f2b(s[7]) << 16);
  return o;
}

// ---------------- gather: x[t,e] = word_embeds[sentence[t], e] ----------------
__global__ void k_gather(const int* __restrict__ sent, const float* __restrict__ we,
                         float* __restrict__ x){
  int idx = blockIdx.x*256 + threadIdx.x;
  if (idx < T_LEN*E_DIM){
    int t = idx / E_DIM, e = idx - t*E_DIM;
    x[idx] = we[(size_t)sent[t]*E_DIM + e];
  }
}

// ---------------- zero the tagged h ring buffer (2 dir * 2 slot * 512 u32) ----
__global__ void k_init(unsigned* __restrict__ hbuf){
  int i = blockIdx.x*256 + threadIdx.x;
  if (i < 2048) hbuf[i] = 0u;  // tag 0, f16 value +0.0
}

// ---------------- MFMA bf16 GEMM: C = act( A(·rev?) * B^T + bias ) ------------
// (unchanged from round 3 — verified)
__global__ __launch_bounds__(256) void k_gemm_mfma(
    const float* __restrict__ Af, int lda, int arev,
    const float* __restrict__ Bf, const unsigned short* __restrict__ Bh, int ldb,
    const float* __restrict__ bias, int act,
    float* __restrict__ C, int ldc, int M, int N, int K)
{
  __shared__ __align__(16) unsigned short As[64*40];
  __shared__ __align__(16) unsigned short Bs[64*40];
  const int tid = threadIdx.x;
  const int bm = blockIdx.y*64, bn = blockIdx.x*64;
  const int r  = tid >> 2, c8 = (tid & 3) * 8;
  const int wave = tid >> 6, lane = tid & 63;
  const int wm = (wave >> 1) * 32, wn = (wave & 1) * 32;
  const int col = lane & 15, quad = lane >> 4;

  const int am = arev ? (M-1-(bm+r)) : (bm+r);
  const float* arow = Af + (size_t)am*lda;
  const float* brow = Bf ? (Bf + (size_t)(bn+r)*ldb) : (const float*)0;
  const unsigned short* brh = Bh ? (Bh + (size_t)(bn+r)*ldb) : (const unsigned short*)0;

  uint4* aw = (uint4*)(As + r*40 + c8);
  uint4* bw = (uint4*)(Bs + r*40 + c8);

  f32x4 acc[2][2];
  #pragma unroll
  for (int i=0;i<2;i++)
    #pragma unroll
    for (int j=0;j<2;j++) acc[i][j] = (f32x4){0.f,0.f,0.f,0.f};

  for (int k0 = 0; k0 < K; k0 += 32){
    uint4 avv, bvv;
    if (k0 + 32 <= K){
      avv = pack8(arow + k0 + c8);
      bvv = Bh ? *(const uint4*)(brh + k0 + c8) : pack8(brow + k0 + c8);
    } else {
      float ta[8], tb[8];
      #pragma unroll
      for (int i=0;i<8;i++){
        const int kk = k0 + c8 + i;
        ta[i] = (kk < K) ? arow[kk] : 0.f;
        tb[i] = (kk < K && Bf) ? brow[kk] : 0.f;
      }
      avv = pack8(ta); bvv = pack8(tb);
    }
    if (k0) __syncthreads();
    *aw = avv; *bw = bvv;
    __syncthreads();
    const short8x a0 = *(const short8x*)(As + (wm+col)*40    + quad*8);
    const short8x a1 = *(const short8x*)(As + (wm+16+col)*40 + quad*8);
    const short8x b0 = *(const short8x*)(Bs + (wn+col)*40    + quad*8);
    const short8x b1 = *(const short8x*)(Bs + (wn+16+col)*40 + quad*8);
    acc[0][0] = __builtin_amdgcn_mfma_f32_16x16x32_bf16(a0, b0, acc[0][0], 0, 0, 0);
    acc[0][1] = __builtin_amdgcn_mfma_f32_16x16x32_bf16(a0, b1, acc[0][1], 0, 0, 0);
    acc[1][0] = __builtin_amdgcn_mfma_f32_16x16x32_bf16(a1, b0, acc[1][0], 0, 0, 0);
    acc[1][1] = __builtin_amdgcn_mfma_f32_16x16x32_bf16(a1, b1, acc[1][1], 0, 0, 0);
  }

  #pragma unroll
  for (int mt=0;mt<2;mt++){
    #pragma unroll
    for (int nt=0;nt<2;nt++){
      const int cc = bn + wn + 16*nt + col;
      const float bs = bias ? bias[cc] : 0.f;
      #pragma unroll
      for (int i=0;i<4;i++){
        const int rr = bm + wm + 16*mt + quad*4 + i;
        float v = acc[mt][nt][i] + bs;
        if (act) v = ftanh(v);
        C[(size_t)rr*ldc + cc] = v;
      }
    }
  }
}

// ---------------- persistent bidirectional LSTM recurrence (MFMA) -------------
// 64 WGs x 256 threads. blocks 0..31: forward, 32..63: backward.
// WG w owns h-units [w*16, w*16+16); wave g (0..3) computes gate g's 16 rows
// as one 16-row MFMA tile over K=512 = 16 x mfma_f32_16x16x32_bf16, with the
// weights held in 16 short8 A-frags (64 VGPRs, preloaded once).
// B operand: h replicated across all 16 N-columns -> the B-frag LDS read is a
// 4-address broadcast b128, and every lane holds the matvec result.
// h broadcast between WGs: hbuf[dir][slot][512] u32 = (tag<<16)|f16, AGENT
// scope (protocol identical to the verified round-0 design).
__global__ __launch_bounds__(256, 1) void k_lstm(
    const float* __restrict__ Whh_f, const float* __restrict__ Whh_b,
    const float* __restrict__ bih_f, const float* __restrict__ bhh_f,
    const float* __restrict__ bih_b, const float* __restrict__ bhh_b,
    const float* __restrict__ xg_f, const float* __restrict__ xg_b,
    unsigned* __restrict__ hbuf, float* __restrict__ enc)
{
  const int dir = blockIdx.x >> 5;
  const int w   = blockIdx.x & 31;
  const int tid = threadIdx.x;
  const int wave = tid >> 6, lane = tid & 63;
  const int col = lane & 15, quad = lane >> 4;

  const float* Whh = dir ? Whh_b : Whh_f;
  const float* xg  = dir ? xg_b  : xg_f;

  // ---- A-frag preload: wave 'wave' = gate, rows rowA = gate*512 + w*16 + col
  const int rowA = wave*H_DIM + w*16 + col;
  short8x w_frag[16];
  #pragma unroll
  for (int s=0;s<16;s++){
    const float* bp = Whh + (size_t)rowA*H_DIM + s*32 + quad*8;
    uint4 u = pack8(bp);
    w_frag[s] = *reinterpret_cast<short8x*>(&u);
  }

  // ---- wave-0 per-gate-value state (tid<64): bias, xg pipeline
  float bias_r = 0.f, xg_cur = 0.f, c_reg = 0.f;
  int row2 = 0;
  if (tid < 64){
    row2 = (tid >> 4)*H_DIM + w*16 + (tid & 15);
    bias_r = dir ? (bih_b[row2] + bhh_b[row2]) : (bih_f[row2] + bhh_f[row2]);
    xg_cur = xg[row2];              // step t=1 uses xg row 0
  }

  __shared__ __align__(16) unsigned short lds_hb[512];  // h_{t-1} as bf16
  __shared__ __align__(16) float raw[64];               // gate pre-activations

  unsigned* hb = hbuf + dir*1024;  // [2][512]

  for (int t = 1; t <= T_LEN; ++t){
    // ---- stage h_{t-1}: poll 2 tagged words/thread, decode f16 -> bf16 LDS
    {
      unsigned* s0 = hb + ((t-1)&1)*512 + tid;
      const unsigned want = (unsigned)(t-1);
      unsigned v0 = __hip_atomic_load(s0,     __ATOMIC_RELAXED, __HIP_MEMORY_SCOPE_AGENT);
      unsigned v1 = __hip_atomic_load(s0+256, __ATOMIC_RELAXED, __HIP_MEMORY_SCOPE_AGENT);
      while (((v0 >> 16) != want) || ((v1 >> 16) != want)){
        v0 = __hip_atomic_load(s0,     __ATOMIC_RELAXED, __HIP_MEMORY_SCOPE_AGENT);
        v1 = __hip_atomic_load(s0+256, __ATOMIC_RELAXED, __HIP_MEMORY_SCOPE_AGENT);
      }
      lds_hb[tid]     = f2b(__half2float(__ushort_as_half((unsigned short)(v0 & 0xffffu))));
      lds_hb[tid+256] = f2b(__half2float(__ushort_as_half((unsigned short)(v1 & 0xffffu))));
    }
    __syncthreads();

    // prefetch next step's xg (consumed next iteration; ~1 step of cover)
    float xg_nxt = 0.f;
    if (tid < 64 && t < T_LEN) xg_nxt = xg[(size_t)t*G4 + row2];

    // ---- matvec: 16 chained-by-2 MFMAs, B = h broadcast-replicated
    f32x4 a0 = (f32x4){0.f,0.f,0.f,0.f}, a1 = (f32x4){0.f,0.f,0.f,0.f};
    #pragma unroll
    for (int s=0;s<16;s+=2){
      const short8x b0 = *(const short8x*)(lds_hb + s*32     + quad*8);
      const short8x b1 = *(const short8x*)(lds_hb + (s+1)*32 + quad*8);
      a0 = __builtin_amdgcn_mfma_f32_16x16x32_bf16(w_frag[s],   b0, a0, 0, 0, 0);
      a1 = __builtin_amdgcn_mfma_f32_16x16x32_bf16(w_frag[s+1], b1, a1, 0, 0, 0);
    }
    if (col == 0){
      f32x4 asum = a0 + a1;   // D[m] in regs i: m = quad*4+i (same for all cols)
      *reinterpret_cast<f32x4*>(raw + wave*16 + quad*4) = asum;
    }
    __syncthreads();

    // ---- gates + state update, all inside wave 0 (shfl handoff, no barrier)
    if (tid < 64){
      float v = raw[tid] + bias_r + xg_cur;
      const float va = ((tid >> 4) == 2) ? ftanh(v) : sigm(v);
      const int l2 = tid & 15;
      const float iv = __shfl(va, l2);
      const float fv = __shfl(va, l2 + 16);
      const float gg = __shfl(va, l2 + 32);
      const float ov = __shfl(va, l2 + 48);
      if (tid < 16){
        c_reg = fv*c_reg + iv*gg;
        const float hh = ov*ftanh(c_reg);
        const int hj = w*16 + tid;
        // publish FIRST (what other WGs wait on)
        const unsigned hv = ((unsigned)t << 16) |
                            (unsigned)__half_as_ushort(__float2half(hh));
        __hip_atomic_store(hb + (t&1)*512 + hj, hv,
                           __ATOMIC_RELAXED, __HIP_MEMORY_SCOPE_AGENT);
        const int tt = dir ? (T_LEN - t) : (t - 1);
        enc[(size_t)tt*D_DIM + dir*H_DIM + hj] = hh;
      }
      xg_cur = xg_nxt;
    }
    __syncthreads();  // protect lds_hb / raw reuse next iteration
  }
}

// ---------------- row softmax in place, rows of 1024 --------------------------
__global__ __launch_bounds__(256) void k_softmax(float* __restrict__ S){
  float* r = S + (size_t)blockIdx.x*1024;
  const int tid = threadIdx.x;
  float v[4];
  #pragma unroll
  for (int i=0;i<4;i++) v[i] = r[tid + i*256];
  float m = fmaxf(fmaxf(v[0],v[1]), fmaxf(v[2],v[3]));
  #pragma unroll
  for (int off=32; off>=1; off>>=1) m = fmaxf(m, __shfl_xor(m, off));
  __shared__ float red[4], red2[4];
  const int wid = tid >> 6, lane = tid & 63;
  if (lane == 0) red[wid] = m;
  __syncthreads();
  m = fmaxf(fmaxf(red[0],red[1]), fmaxf(red[2],red[3]));
  float s = 0.f;
  #pragma unroll
  for (int i=0;i<4;i++){ v[i] = __expf(v[i]-m); s += v[i]; }
  #pragma unroll
  for (int off=32; off>=1; off>>=1) s += __shfl_xor(s, off);
  if (lane == 0) red2[wid] = s;
  __syncthreads();
  s = red2[0]+red2[1]+red2[2]+red2[3];
  const float inv = frcp(s);
  #pragma unroll
  for (int i=0;i<4;i++) r[tid + i*256] = v[i]*inv;
}

// ---------------- copy enc into cat[:, 0:1024] (f32) --------------------------
__global__ void k_copy_enc(const float* __restrict__ enc, float* __restrict__ cat){
  int idx = blockIdx.x*256 + threadIdx.x;
  if (idx < T_LEN*D_DIM){
    int t = idx >> 10, d = idx & 1023;
    cat[(size_t)t*2048 + d] = enc[idx];
  }
}

// ---------------- transpose-cast: encT_bf16[d][t] = bf16(enc[t][d]) -----------
__global__ __launch_bounds__(256) void k_castT(const float* __restrict__ src,
                                               unsigned short* __restrict__ dst){
  __shared__ float tile[32][33];
  const int bx = blockIdx.x*32, by = blockIdx.y*32;
  const int tx = threadIdx.x & 31, ty8 = threadIdx.x >> 5;
  #pragma unroll
  for (int i=ty8;i<32;i+=8) tile[i][tx] = src[(size_t)(by+i)*1024 + bx+tx];
  __syncthreads();
  #pragma unroll
  for (int i=ty8;i<32;i+=8) dst[(size_t)(bx+i)*1024 + by+tx] = f2b(tile[tx][i]);
}

// ---------------- feats = h1 * tag_W^T + tag_b  [1024,12] ---------------------
// one block per timestep; wave g computes tags 3g..3g+2, h1 row reused in regs
__global__ __launch_bounds__(256) void k_feats(
    const float* __restrict__ h1, const float* __restrict__ tagW,
    const float* __restrict__ tagb, float* __restrict__ feats)
{
  const int t = blockIdx.x;
  const int wave = threadIdx.x >> 6, lane = threadIdx.x & 63;
  const float* hr = h1 + (size_t)t*D_DIM;
  float hv[16];
  #pragma unroll
  for (int i=0;i<16;i++) hv[i] = hr[lane + 64*i];
  #pragma unroll
  for (int j=0;j<3;j++){
    const int tag = wave*3 + j;
    const float* wr = tagW + (size_t)tag*D_DIM;
    float s = 0.f;
    #pragma unroll
    for (int i=0;i<16;i++) s += hv[i]*wr[lane + 64*i];
    #pragma unroll
    for (int off=32; off>=1; off>>=1) s += __shfl_xor(s, off);
    if (lane == 0) feats[(size_t)t*K_TAGS + tag] = s + tagb[tag];
  }
}

// ---------------- CRF forward + gold score, single wave -----------------------
__global__ void k_crf(const float* __restrict__ feats, const float* __restrict__ trans,
                      const int* __restrict__ tags, float* __restrict__ out){
  const int tid = threadIdx.x;  // 64 threads, one wave
  float gold = 0.f;
  for (int i = tid; i <= T_LEN; i += 64){
    const int to = (i < T_LEN) ? tags[i]   : 11;        // STOP
    const int fr = (i == 0)    ? 10        : tags[i-1]; // START
    gold += trans[to*K_TAGS + fr];
    if (i < T_LEN) gold += feats[(size_t)i*K_TAGS + tags[i]];
  }
  #pragma unroll
  for (int off=32; off>=1; off>>=1) gold += __shfl_xor(gold, off);

  float Trow[K_TAGS];
  if (tid < K_TAGS){
    #pragma unroll
    for (int j=0;j<K_TAGS;j++) Trow[j] = trans[tid*K_TAGS + j];
  }
  float alpha = (tid == 10) ? 0.f : -10000.f;
  for (int t=0;t<T_LEN;++t){
    float av[K_TAGS];
    #pragma unroll
    for (int j=0;j<K_TAGS;j++) av[j] = __shfl(alpha, j);
    if (tid < K_TAGS){
      float vv[K_TAGS], m = -1e30f;
      #pragma unroll
      for (int j=0;j<K_TAGS;j++){ vv[j] = av[j] + Trow[j]; m = fmaxf(m, vv[j]); }
      float s = 0.f;
      #pragma unroll
      for (int j=0;j<K_TAGS;j++) s += __expf(vv[j]-m);
      alpha = m + __logf(s) + feats[(size_t)t*K_TAGS + tid];
    }
  }
  float v = (tid < K_TAGS) ? (alpha + trans[11*K_TAGS + tid]) : -1e30f;
  float m = v;
  #pragma unroll
  for (int off=32; off>=1; off>>=1) m = fmaxf(m, __shfl_xor(m, off));
  float e = (tid < K_TAGS) ? __expf(v - m) : 0.f;
  #pragma unroll
  for (int off=32; off>=1; off>>=1) e += __shfl_xor(e, off);
  if (tid == 0) out[0] = (m + __logf(e)) - gold;
}

// ------------------------------------------------------------------------------
extern "C" void kernel_launch(void* const* d_in, const int* in_sizes, int n_in,
                              void* d_out, int out_size, void* d_ws, size_t ws_size,
                              hipStream_t stream)
{
  const int*   sentence = (const int*)d_in[0];
  const int*   tags     = (const int*)d_in[1];
  const float* we       = (const float*)d_in[2];
  const float* Wih_f    = (const float*)d_in[3];
  const float* Whh_f    = (const float*)d_in[4];
  const float* bih_f    = (const float*)d_in[5];
  const float* bhh_f    = (const float*)d_in[6];
  const float* Wih_b    = (const float*)d_in[7];
  const float* Whh_b    = (const float*)d_in[8];
  const float* bih_b    = (const float*)d_in[9];
  const float* bhh_b    = (const float*)d_in[10];
  const float* attn_W   = (const float*)d_in[11];
  const float* attn_b   = (const float*)d_in[12];
  const float* h2h1_W   = (const float*)d_in[13];
  const float* h2h1_b   = (const float*)d_in[14];
  const float* tag_W    = (const float*)d_in[15];
  const float* tag_b    = (const float*)d_in[16];
  const float* trans    = (const float*)d_in[17];
  float* out = (float*)d_out;

  // workspace layout (floats) — identical footprint to the proven pool
  float* ws     = (float*)d_ws;
  float* cat    = ws;                  // [1024,2048]   also xg_f
  float* reg2   = cat  + 2097152;      // [2M]          xg_b; later scores+h1
  float* enc    = reg2 + 2097152;      // [1024,1024]
  float* proj   = enc  + 1048576;      // [1024,1024]   also x; later encT_bf16
  float* feats  = proj + 1048576;      // [1024,12]
  unsigned* hbuf= (unsigned*)(feats + 12288);  // 2048 u32
  float* xg_f   = cat;
  float* xg_b   = reg2;
  float* scores = reg2;
  float* h1     = reg2 + 1048576;
  float* x      = proj;
  unsigned short* encT = (unsigned short*)proj;  // 2 MiB, used after proj dead

  // 1. gather embeddings
  k_gather<<<dim3((T_LEN*E_DIM + 255)/256), dim3(256), 0, stream>>>(sentence, we, x);
  // 2. init h ring buffer
  k_init<<<dim3(8), dim3(256), 0, stream>>>(hbuf);
  // 3. xg_f = x * Wih_f^T        [1024,2048], K=300 ragged
  k_gemm_mfma<<<dim3(32,16), dim3(256), 0, stream>>>(x, E_DIM, 0,
      Wih_f, nullptr, E_DIM, nullptr, 0, xg_f, G4, T_LEN, G4, E_DIM);
  // 4. xg_b = rev(x) * Wih_b^T   [1024,2048]
  k_gemm_mfma<<<dim3(32,16), dim3(256), 0, stream>>>(x, E_DIM, 1,
      Wih_b, nullptr, E_DIM, nullptr, 0, xg_b, G4, T_LEN, G4, E_DIM);
  // 5. bidirectional recurrence -> enc [1024,1024]  (MFMA matvec, 64 WGs)
  k_lstm<<<dim3(64), dim3(256), 0, stream>>>(Whh_f, Whh_b, bih_f, bhh_f,
      bih_b, bhh_b, xg_f, xg_b, hbuf, enc);
  // 6. proj = enc * attn_W^T + attn_b
  k_gemm_mfma<<<dim3(16,16), dim3(256), 0, stream>>>(enc, D_DIM, 0,
      attn_W, nullptr, D_DIM, attn_b, 0, proj, D_DIM, T_LEN, D_DIM, D_DIM);
  // 7. scores = enc * proj^T
  k_gemm_mfma<<<dim3(16,16), dim3(256), 0, stream>>>(enc, D_DIM, 0,
      proj, nullptr, D_DIM, nullptr, 0, scores, T_LEN, T_LEN, T_LEN, D_DIM);
  // 8. row softmax in place
  k_softmax<<<dim3(1024), dim3(256), 0, stream>>>(scores);
  // 9. cat[:, :1024] = enc   (f32)
  k_copy_enc<<<dim3(4096), dim3(256), 0, stream>>>(enc, cat);
  // 10. encT_bf16 = enc^T    (proj region is dead now)
  k_castT<<<dim3(32,32), dim3(256), 0, stream>>>(enc, encT);
  // 11. cat[:, 1024:] = w * enc  via A=w, B=encT (bf16 precast)
  k_gemm_mfma<<<dim3(16,16), dim3(256), 0, stream>>>(scores, T_LEN, 0,
      nullptr, encT, D_DIM, nullptr, 0, cat + 1024, 2048, T_LEN, D_DIM, T_LEN);
  // 12. h1 = tanh(cat * h2h1_W^T + h2h1_b), K=2048
  k_gemm_mfma<<<dim3(16,16), dim3(256), 0, stream>>>(cat, 2048, 0,
      h2h1_W, nullptr, 2048, h2h1_b, 1, h1, D_DIM, T_LEN, D_DIM, 2048);
  // 13. feats = h1 * tag_W^T + tag_b   [1024,12]
  k_feats<<<dim3(1024), dim3(256), 0, stream>>>(h1, tag_W, tag_b, feats);
  // 14. CRF NLL
  k_crf<<<dim3(1), dim3(64), 0, stream>>>(feats, trans, tags, out);
}